// Round 11
// baseline (199.595 us; speedup 1.0000x reference)
//
#include <hip/hip_runtime.h>

constexpr int BATCH = 1048576;
constexpr int H = 20;        // hidden
constexpr int BLK = 256;     // threads per block
constexpr int RPB = 512;     // rows per block (2 per thread)
constexpr int RS = 21;       // padded LDS row stride (conflict-benign)
constexpr unsigned CAP = 32768;
constexpr float EPS_GUARD = 1e-4f;   // validated R6-R8 (fast-cdf err ~3e-5)

// ---- d_ws layout (bytes) ----
constexpr size_t CNT_B  = 0;         // u32 counter
constexpr size_t WPK_B  = 4096;      // packed weights, 1840 floats
constexpr size_t LIST_B = 16384;     // u32[CAP]
// packed float offsets (relative to WPK_B), identical to validated R5-R10:
constexpr int WHH_OFF = 0;      // (q*20+k)*4 + gate {i,f,g,o}
constexpr int WIH_OFF = 1600;   // q*8 + {gate, 4+gate} for x0,x1
constexpr int B_OFF   = 1760;   // q*4 + gate (b_ih+b_hh pre-summed)

typedef float v2f __attribute__((ext_vector_type(2)));
__device__ __forceinline__ v2f splat2(float s) { v2f r; r.x = s; r.y = s; return r; }

// ---- exact path (bit-identical to validated R3/R5-R10) ----
__device__ __forceinline__ float sigmoidf_stable(float z) {
    const float e = expf(-fabsf(z));
    const float n = (z >= 0.0f) ? 1.0f : e;
    return n / (1.0f + e);
}
// ---- fast path (validated R6-R10) ----
__device__ __forceinline__ float fsigmoid(float z) {
    const float e = __expf(-z);
    return __builtin_amdgcn_rcpf(1.0f + e);
}
__device__ __forceinline__ float ftanh(float z) {
    const float e = __expf(2.0f * z);
    return 1.0f - 2.0f * __builtin_amdgcn_rcpf(e + 1.0f);
}

__global__ __launch_bounds__(256) void pack_weights(
    const float* __restrict__ W_ih, const float* __restrict__ W_hh,
    const float* __restrict__ b_ih, const float* __restrict__ b_hh,
    char* __restrict__ wsb)
{
    float* ws = (float*)(wsb + WPK_B);
    const int i = blockIdx.x * 256 + threadIdx.x;
    if (i == 0) *(unsigned*)(wsb + CNT_B) = 0u;
    if (i < 400) {
        const int q = i / 20, k = i % 20;
#pragma unroll
        for (int g = 0; g < 4; ++g)
            ws[WHH_OFF + i * 4 + g] = W_hh[(g * 20 + q) * 20 + k];
    }
    if (i < 20) {
#pragma unroll
        for (int g = 0; g < 4; ++g) {
            ws[WIH_OFF + i * 8 + g]     = W_ih[(g * 20 + i) * 2 + 0];
            ws[WIH_OFF + i * 8 + 4 + g] = W_ih[(g * 20 + i) * 2 + 1];
            ws[B_OFF   + i * 4 + g]     = b_ih[g * 20 + i] + b_hh[g * 20 + i];
        }
    }
}

__device__ __forceinline__ void fast_sample(float L0, float L1, float L2, float uv,
                                            float& act, float& slp, float& dmin) {
    const float m = fmaxf(fmaxf(L0, L1), L2);
    const float s = __expf(L0 - m) + __expf(L1 - m) + __expf(L2 - m);
    const float lse = m + __logf(s);
    const float lp0 = L0 - lse, lp1 = L1 - lse, lp2 = L2 - lse;
    const float p0 = __expf(lp0), p1 = __expf(lp1), p2 = __expf(lp2);
    const float c0 = p0, c1 = c0 + p1, c2 = c1 + p2;
    int a = (int)(c0 < uv) + (int)(c1 < uv) + (int)(c2 < uv);
    a = a > 2 ? 2 : a;
    act = (float)a;
    slp = (a == 0) ? lp0 : ((a == 1) ? lp1 : lp2);
    dmin = fminf(fminf(fabsf(c0 - uv), fabsf(c1 - uv)), fabsf(c2 - uv));
}

__global__ __launch_bounds__(BLK) void lstm_coord_kernel(
    const float* __restrict__ x,
    const float* __restrict__ hx,
    const float* __restrict__ cx,
    const float* __restrict__ u,
    const char* __restrict__ wsb,
    const float* __restrict__ W_dec,
    const float* __restrict__ b_dec,
    float* __restrict__ out,
    unsigned* __restrict__ cnt,
    unsigned* __restrict__ list)
{
    // LDS: one half-tile (256 rows) of h and c for store coalescing.
    __shared__ float sH[256 * RS];
    __shared__ float sC[256 * RS];

    const float* wpk = (const float*)(wsb + WPK_B);
    const int t = threadIdx.x;
    const int r0g = blockIdx.x * RPB + 2 * t;          // this thread's row pair
    const size_t rowbase = (size_t)r0g * H;            // 160B-aligned

    // ---- direct register loads of both rows (contiguous 160B per thread) ----
    v2f hv2[H];            // {row0, row1}
    v2f cxv[H];            // becomes c-out in place
    {
        float a[2 * H], c[2 * H];
#pragma unroll
        for (int j = 0; j < 10; ++j) {
            const float4 q4 = *reinterpret_cast<const float4*>(hx + rowbase + 4 * j);
            a[4 * j] = q4.x; a[4 * j + 1] = q4.y; a[4 * j + 2] = q4.z; a[4 * j + 3] = q4.w;
            const float4 c4 = *reinterpret_cast<const float4*>(cx + rowbase + 4 * j);
            c[4 * j] = c4.x; c[4 * j + 1] = c4.y; c[4 * j + 2] = c4.z; c[4 * j + 3] = c4.w;
        }
#pragma unroll
        for (int k = 0; k < H; ++k) {
            hv2[k].x = a[k]; hv2[k].y = a[H + k];
            cxv[k].x = c[k]; cxv[k].y = c[H + k];
        }
    }
    const float4 xq = *reinterpret_cast<const float4*>(x + 2 * (size_t)r0g);
    v2f x0v; x0v.x = xq.x; x0v.y = xq.z;
    v2f x1v; x1v.x = xq.y; x1v.y = xq.w;
    const float2 uv2 = *reinterpret_cast<const float2*>(u + (size_t)r0g);

    // ---- FAST path: 2 rows packed, 4 independent gate chains ----
    // Per-component op order identical to validated R10.
    v2f hqv[H];
    v2f l0v = splat2(b_dec[0]), l1v = splat2(b_dec[1]), l2v = splat2(b_dec[2]);
#pragma unroll 1
    for (int q = 0; q < H; ++q) {
        const float4 bq  = *reinterpret_cast<const float4*>(wpk + B_OFF + 4 * q);
        const float4 wx0 = *reinterpret_cast<const float4*>(wpk + WIH_OFF + 8 * q);
        const float4 wx1 = *reinterpret_cast<const float4*>(wpk + WIH_OFF + 8 * q + 4);
        v2f ai = splat2(bq.x) + x0v * splat2(wx0.x) + x1v * splat2(wx1.x);
        v2f af = splat2(bq.y) + x0v * splat2(wx0.y) + x1v * splat2(wx1.y);
        v2f ag = splat2(bq.z) + x0v * splat2(wx0.z) + x1v * splat2(wx1.z);
        v2f ao = splat2(bq.w) + x0v * splat2(wx0.w) + x1v * splat2(wx1.w);
#pragma unroll
        for (int k = 0; k < H; ++k) {
            const float4 wq = *reinterpret_cast<const float4*>(wpk + WHH_OFF + (q * 20 + k) * 4);
            const v2f hk = hv2[k];
            ai += hk * splat2(wq.x);
            af += hk * splat2(wq.y);
            ag += hk * splat2(wq.z);
            ao += hk * splat2(wq.w);
        }
        v2f gi, gf, gg, go;
        gi.x = fsigmoid(ai.x); gi.y = fsigmoid(ai.y);
        gf.x = fsigmoid(af.x); gf.y = fsigmoid(af.y);
        gg.x = ftanh(ag.x);    gg.y = ftanh(ag.y);
        go.x = fsigmoid(ao.x); go.y = fsigmoid(ao.y);
        const v2f cq = gf * cxv[q] + gi * gg;
        v2f th; th.x = ftanh(cq.x); th.y = ftanh(cq.y);
        const v2f hq = go * th;
        cxv[q] = cq;
        hqv[q] = hq;
        const float wd0 = W_dec[q], wd1 = W_dec[20 + q], wd2 = W_dec[40 + q];
        l0v += hq * splat2(wd0);
        l1v += hq * splat2(wd1);
        l2v += hq * splat2(wd2);
    }

    // ---- fast softmax + inverse-CDF per row; risky rows -> fixup list ----
    {
        float a0, s0, d0, a1, s1, d1;
        fast_sample(l0v.x, l1v.x, l2v.x, uv2.x, a0, s0, d0);
        fast_sample(l0v.y, l1v.y, l2v.y, uv2.y, a1, s1, d1);
        *reinterpret_cast<float2*>(out + (size_t)r0g) = make_float2(a0, a1);
        *reinterpret_cast<float2*>(out + (size_t)BATCH + r0g) = make_float2(s0, s1);
        if (d0 < EPS_GUARD) {
            const unsigned i = atomicAdd(cnt, 1u);
            if (i < CAP) list[i] = (unsigned)r0g;
        }
        if (d1 < EPS_GUARD) {
            const unsigned i = atomicAdd(cnt, 1u);
            if (i < CAP) list[i] = (unsigned)(r0g + 1);
        }
    }

    // ---- two half-tile store phases (wave-uniform branches) ----
    float* hout  = out + 2 * (size_t)BATCH;
    float* cout_ = hout + (size_t)H * BATCH;
    const size_t base10 = (size_t)blockIdx.x * (RPB * H);

    // phase A: rows 0..255 (threads 0..127 own them)
    if (t < 128) {
        const int ra = (2 * t) * RS, rb = ra + RS;
#pragma unroll
        for (int q = 0; q < H; ++q) {
            sH[ra + q] = hqv[q].x; sH[rb + q] = hqv[q].y;
            sC[ra + q] = cxv[q].x; sC[rb + q] = cxv[q].y;
        }
    }
    __syncthreads();
#pragma unroll
    for (int j = 0; j < 5; ++j) {
        const int g = 4 * (t + BLK * j);
        float4 v, w;
#pragma unroll
        for (int e = 0; e < 4; ++e) {
            const int gg2 = g + e;
            (&v.x)[e] = sH[gg2 + gg2 / H];
            (&w.x)[e] = sC[gg2 + gg2 / H];
        }
        *reinterpret_cast<float4*>(hout  + base10 + g) = v;
        *reinterpret_cast<float4*>(cout_ + base10 + g) = w;
    }
    __syncthreads();
    // phase B: rows 256..511 (threads 128..255 own them)
    if (t >= 128) {
        const int tt = t - 128;
        const int ra = (2 * tt) * RS, rb = ra + RS;
#pragma unroll
        for (int q = 0; q < H; ++q) {
            sH[ra + q] = hqv[q].x; sH[rb + q] = hqv[q].y;
            sC[ra + q] = cxv[q].x; sC[rb + q] = cxv[q].y;
        }
    }
    __syncthreads();
#pragma unroll
    for (int j = 0; j < 5; ++j) {
        const int g = 4 * (t + BLK * j);
        float4 v, w;
#pragma unroll
        for (int e = 0; e < 4; ++e) {
            const int gg2 = g + e;
            (&v.x)[e] = sH[gg2 + gg2 / H];
            (&w.x)[e] = sC[gg2 + gg2 / H];
        }
        *reinterpret_cast<float4*>(hout  + base10 + 5120 + g) = v;
        *reinterpret_cast<float4*>(cout_ + base10 + 5120 + g) = w;
    }
}

// ---- exact fixup on the sparse risky list (validated R9 path) ----
__global__ __launch_bounds__(256) void lstm_fixup(
    const float* __restrict__ x, const float* __restrict__ hx,
    const float* __restrict__ cx, const float* __restrict__ u,
    const float* __restrict__ W_ih, const float* __restrict__ W_hh,
    const float* __restrict__ b_ih, const float* __restrict__ b_hh,
    const float* __restrict__ W_dec, const float* __restrict__ b_dec,
    const unsigned* __restrict__ cnt, const unsigned* __restrict__ list,
    float* __restrict__ out)
{
    const unsigned n = min(*cnt, CAP);
    const unsigned i = blockIdx.x * 256 + threadIdx.x;
    if (i >= n) return;
    const int b = (int)list[i];
    const float x0 = x[2 * (size_t)b], x1 = x[2 * (size_t)b + 1];
    const float uv = u[b];
    float hv[H], cvv[H];
#pragma unroll
    for (int k = 0; k < H; ++k) {
        hv[k]  = hx[(size_t)b * H + k];
        cvv[k] = cx[(size_t)b * H + k];
    }
    float l0 = b_dec[0], l1 = b_dec[1], l2 = b_dec[2];
#pragma unroll 1
    for (int q = 0; q < H; ++q) {
        float gi = (b_ih[q]      + b_hh[q])      + x0 * W_ih[2 * q]          + x1 * W_ih[2 * q + 1];
        float gf = (b_ih[20 + q] + b_hh[20 + q]) + x0 * W_ih[2 * (20 + q)]   + x1 * W_ih[2 * (20 + q) + 1];
        float gg = (b_ih[40 + q] + b_hh[40 + q]) + x0 * W_ih[2 * (40 + q)]   + x1 * W_ih[2 * (40 + q) + 1];
        float go = (b_ih[60 + q] + b_hh[60 + q]) + x0 * W_ih[2 * (60 + q)]   + x1 * W_ih[2 * (60 + q) + 1];
#pragma unroll
        for (int k = 0; k < H; ++k) {
            const float hk = hv[k];
            gi += hk * W_hh[(q)      * H + k];
            gf += hk * W_hh[(20 + q) * H + k];
            gg += hk * W_hh[(40 + q) * H + k];
            go += hk * W_hh[(60 + q) * H + k];
        }
        gi = sigmoidf_stable(gi);
        gf = sigmoidf_stable(gf);
        gg = tanhf(gg);
        go = sigmoidf_stable(go);
        const float cq = gf * cvv[q] + gi * gg;
        const float hq = go * tanhf(cq);
        l0 += hq * W_dec[q];
        l1 += hq * W_dec[20 + q];
        l2 += hq * W_dec[40 + q];
    }
    const float m = fmaxf(fmaxf(l0, l1), l2);
    const float s = expf(l0 - m) + expf(l1 - m) + expf(l2 - m);
    const float lse = m + logf(s);
    const float lp0 = l0 - lse, lp1 = l1 - lse, lp2 = l2 - lse;
    const float p0 = expf(lp0), p1 = expf(lp1), p2 = expf(lp2);
    const float c0 = p0, c1 = c0 + p1, c2 = c1 + p2;
    int ae = (int)(c0 < uv) + (int)(c1 < uv) + (int)(c2 < uv);
    ae = ae > 2 ? 2 : ae;
    out[b] = (float)ae;
    out[(size_t)BATCH + b] = (ae == 0) ? lp0 : ((ae == 1) ? lp1 : lp2);
}

extern "C" void kernel_launch(void* const* d_in, const int* in_sizes, int n_in,
                              void* d_out, int out_size, void* d_ws, size_t ws_size,
                              hipStream_t stream) {
    const float* x     = (const float*)d_in[0];
    const float* hx    = (const float*)d_in[1];
    const float* cx    = (const float*)d_in[2];
    const float* u     = (const float*)d_in[3];
    const float* W_ih  = (const float*)d_in[4];
    const float* W_hh  = (const float*)d_in[5];
    const float* b_ih  = (const float*)d_in[6];
    const float* b_hh  = (const float*)d_in[7];
    const float* W_dec = (const float*)d_in[8];
    const float* b_dec = (const float*)d_in[9];
    float* out = (float*)d_out;
    char* wsb = (char*)d_ws;
    unsigned* cnt  = (unsigned*)(wsb + CNT_B);
    unsigned* list = (unsigned*)(wsb + LIST_B);

    pack_weights<<<2, 256, 0, stream>>>(W_ih, W_hh, b_ih, b_hh, wsb);
    lstm_coord_kernel<<<BATCH / RPB, BLK, 0, stream>>>(
        x, hx, cx, u, wsb, W_dec, b_dec, out, cnt, list);
    lstm_fixup<<<CAP / 256, 256, 0, stream>>>(x, hx, cx, u, W_ih, W_hh, b_ih, b_hh,
                                              W_dec, b_dec, cnt, list, out);
}

// Round 12
// 135.943 us; speedup vs baseline: 1.4682x; 1.4682x over previous
//
#include <hip/hip_runtime.h>

constexpr int BATCH = 1048576;
constexpr int H = 20;
constexpr unsigned CAP = 32768;          // fixup list capacity (expect ~3k entries)
constexpr float EPS_GUARD = 1e-3f;       // validated R9 (f16 3-pass err << 1e-4)

// ---- d_ws byte offsets (R9-validated sizes, ~151KB total) ----
constexpr size_t CNT_OFF  = 0;                       // u32 counter
constexpr size_t LIST_OFF = 4096;                    // u32[CAP]
constexpr size_t WFH_OFF  = 4096 + 131072;           // f16 W-frag hi: 5*64*8
constexpr size_t WFL_OFF  = WFH_OFF + 8192;          // f16 W-frag lo
constexpr size_t B4_OFF   = WFL_OFF + 8192;          // f32 bias4[80]  (4q+g)
constexpr size_t WD4_OFF  = B4_OFF + 512;            // f32 wd4[80]    (4q+a, a<3)

typedef _Float16 f16x8 __attribute__((ext_vector_type(8)));
typedef float    f32x4 __attribute__((ext_vector_type(4)));

// ---- exact path (bit-identical to validated R3/R5-R10) ----
__device__ __forceinline__ float sigmoidf_stable(float z) {
    const float e = expf(-fabsf(z));
    const float n = (z >= 0.0f) ? 1.0f : e;
    return n / (1.0f + e);
}
// ---- fast path (validated R6-R10) ----
__device__ __forceinline__ float fsigmoid(float z) {
    const float e = __expf(-z);
    return __builtin_amdgcn_rcpf(1.0f + e);
}
__device__ __forceinline__ float ftanh(float z) {
    const float e = __expf(2.0f * z);
    return 1.0f - 2.0f * __builtin_amdgcn_rcpf(e + 1.0f);
}

// =====================  weight prep (verbatim R9)  =====================
__global__ __launch_bounds__(256) void pack_weights(
    const float* __restrict__ W_ih, const float* __restrict__ W_hh,
    const float* __restrict__ b_ih, const float* __restrict__ b_hh,
    const float* __restrict__ W_dec, char* __restrict__ ws)
{
    const int idx = blockIdx.x * 256 + threadIdx.x;
    if (idx == 0) *(unsigned*)(ws + CNT_OFF) = 0u;
    if (idx < 2560) {
        // A-frag element (m, lane, j): gate-row 16m+(l&15) (interleaved 4q+g),
        // k = (l>>4)*8 + j.  orig row = g*20+q.
        const int m = idx >> 9;
        const int l = (idx >> 3) & 63;
        const int j = idx & 7;
        const int grow = 16 * m + (l & 15);
        const int q = grow >> 2, g = grow & 3;
        const int orow = g * 20 + q;
        const int k = ((l >> 4) << 3) + j;
        float wv = 0.0f;
        if (k < 20)      wv = W_hh[orow * 20 + k];
        else if (k < 22) wv = W_ih[orow * 2 + (k - 20)];
        const _Float16 hi = (_Float16)wv;
        const _Float16 lo = (_Float16)(wv - (float)hi);
        ((_Float16*)(ws + WFH_OFF))[idx] = hi;
        ((_Float16*)(ws + WFL_OFF))[idx] = lo;
    } else if (idx < 2640) {
        const int i2 = idx - 2560;
        const int q = i2 >> 2, g = i2 & 3;
        ((float*)(ws + B4_OFF))[i2] = b_ih[g * 20 + q] + b_hh[g * 20 + q];
    } else if (idx < 2720) {
        const int i2 = idx - 2640;
        const int q = i2 >> 2, a = i2 & 3;
        ((float*)(ws + WD4_OFF))[i2] = (a < 3) ? W_dec[a * 20 + q] : 0.0f;
    }
}

// =====================  main MFMA kernel (lean scaffolding)  =====================
// Block = 256 rows, wave = 64 rows, wave-autonomous (no barriers).
// vs R9: (1) B-frags loaded per-lane DIRECTLY from global (no LDS transpose
// staging); (2) dedicated [256][20] f32 store tiles: write side exactly 2-way
// bank-aliased (free, m136), read side canonical consecutive-b128, row-major
// -> no /20 divisions in the store phase.
__global__ __launch_bounds__(256) void lstm_mfma(
    const float* __restrict__ x, const float* __restrict__ hx,
    const float* __restrict__ cx, const float* __restrict__ u,
    const char* __restrict__ ws, const float* __restrict__ b_dec,
    float* __restrict__ out, unsigned* __restrict__ cnt,
    unsigned* __restrict__ list)
{
    __shared__ float sH[256 * H];
    __shared__ float sC[256 * H];

    const int t = threadIdx.x;
    const int l = t & 63;
    const int w = t >> 6;
    const int gam = l >> 4;
    const int b0 = blockIdx.x * 256;

    // ---- hoist W fragments / bias / dec (per-lane VMEM, coalesced) ----
    f16x8 wfh[5], wfl[5];
    float4 bias_m[5], wd_m[5];
#pragma unroll
    for (int m = 0; m < 5; ++m) {
        wfh[m] = *(const f16x8*)(ws + WFH_OFF + (size_t)(m * 64 + l) * 16);
        wfl[m] = *(const f16x8*)(ws + WFL_OFF + (size_t)(m * 64 + l) * 16);
        const int qm = 4 * m + gam;
        bias_m[m] = *(const float4*)(ws + B4_OFF + (size_t)qm * 16);
        wd_m[m]   = *(const float4*)(ws + WD4_OFF + (size_t)qm * 16);
    }
    const float bd0 = b_dec[0], bd1 = b_dec[1], bd2 = b_dec[2];

    // ---- 4 groups of 16 rows per wave ----
#pragma unroll
    for (int g = 0; g < 4; ++g) {
        const int rloc = 64 * w + 16 * g + (l & 15);
        const int bg = b0 + rloc;

        // B-fragment: batch row bg, k = 8*gam + j (k>=22 -> 0); direct loads.
        float ff[8] = {0.f, 0.f, 0.f, 0.f, 0.f, 0.f, 0.f, 0.f};
        const float* hxr = hx + (size_t)bg * H;
        if (gam == 0) {
            const float4 a = *(const float4*)(hxr);
            const float4 b = *(const float4*)(hxr + 4);
            ff[0] = a.x; ff[1] = a.y; ff[2] = a.z; ff[3] = a.w;
            ff[4] = b.x; ff[5] = b.y; ff[6] = b.z; ff[7] = b.w;
        } else if (gam == 1) {
            const float4 a = *(const float4*)(hxr + 8);
            const float4 b = *(const float4*)(hxr + 12);
            ff[0] = a.x; ff[1] = a.y; ff[2] = a.z; ff[3] = a.w;
            ff[4] = b.x; ff[5] = b.y; ff[6] = b.z; ff[7] = b.w;
        } else if (gam == 2) {
            const float4 a = *(const float4*)(hxr + 16);
            const float2 xv = *(const float2*)(x + 2 * (size_t)bg);
            ff[0] = a.x; ff[1] = a.y; ff[2] = a.z; ff[3] = a.w;
            ff[4] = xv.x; ff[5] = xv.y;
        }
        f16x8 bhi, blo;
#pragma unroll
        for (int j = 0; j < 8; ++j) {
            const _Float16 h = (_Float16)ff[j];
            bhi[j] = h;
            blo[j] = (_Float16)(ff[j] - (float)h);
        }

        // hoist this group's cx gathers
        float cxv_[5];
#pragma unroll
        for (int m = 0; m < 5; ++m)
            cxv_[m] = cx[(size_t)bg * H + 4 * m + gam];

        float l0 = 0.0f, l1 = 0.0f, l2 = 0.0f;
#pragma unroll
        for (int m = 0; m < 5; ++m) {
            f32x4 acc = {0.0f, 0.0f, 0.0f, 0.0f};
            acc = __builtin_amdgcn_mfma_f32_16x16x32_f16(wfh[m], bhi, acc, 0, 0, 0);
            acc = __builtin_amdgcn_mfma_f32_16x16x32_f16(wfh[m], blo, acc, 0, 0, 0);
            acc = __builtin_amdgcn_mfma_f32_16x16x32_f16(wfl[m], bhi, acc, 0, 0, 0);
            const int q = 4 * m + gam;
            const float gi = fsigmoid(acc[0] + bias_m[m].x);
            const float gf = fsigmoid(acc[1] + bias_m[m].y);
            const float g2 = ftanh  (acc[2] + bias_m[m].z);
            const float go = fsigmoid(acc[3] + bias_m[m].w);
            const float cq = gf * cxv_[m] + gi * g2;
            const float hq = go * ftanh(cq);
            sH[rloc * H + q] = hq;        // 2-way bank alias only (free)
            sC[rloc * H + q] = cq;
            l0 += hq * wd_m[m].x;
            l1 += hq * wd_m[m].y;
            l2 += hq * wd_m[m].z;
        }
        // reduce the 4 lane-group partials of each batch row
        l0 += __shfl_xor(l0, 16); l0 += __shfl_xor(l0, 32);
        l1 += __shfl_xor(l1, 16); l1 += __shfl_xor(l1, 32);
        l2 += __shfl_xor(l2, 16); l2 += __shfl_xor(l2, 32);

        if (l < 16) {
            const float L0 = l0 + bd0, L1 = l1 + bd1, L2 = l2 + bd2;
            const float uv = u[bg];
            const float mm = fmaxf(fmaxf(L0, L1), L2);
            const float ss = __expf(L0 - mm) + __expf(L1 - mm) + __expf(L2 - mm);
            const float lse = mm + __logf(ss);
            const float lp0 = L0 - lse, lp1 = L1 - lse, lp2 = L2 - lse;
            const float p0 = __expf(lp0), p1 = __expf(lp1), p2 = __expf(lp2);
            const float c0 = p0, c1 = c0 + p1, c2 = c1 + p2;
            int acti = (int)(c0 < uv) + (int)(c1 < uv) + (int)(c2 < uv);
            acti = acti > 2 ? 2 : acti;
            out[bg] = (float)acti;
            out[(size_t)BATCH + bg] = (acti == 0) ? lp0 : ((acti == 1) ? lp1 : lp2);
            const float dmin = fminf(fminf(fabsf(c0 - uv), fabsf(c1 - uv)), fabsf(c2 - uv));
            if (dmin < EPS_GUARD) {
                const unsigned i = atomicAdd(cnt, 1u);
                if (i < CAP) list[i] = (unsigned)bg;
            }
        }
    }

    // ---- wave-local coalesced store (row-major tile: no division, no barrier) ----
    float* hout  = out + 2 * (size_t)BATCH;
    float* cout_ = hout + (size_t)H * BATCH;
    const size_t bb = (size_t)blockIdx.x * (256 * H);
#pragma unroll
    for (int jj = 0; jj < 5; ++jj) {
        const int f = 1280 * w + 4 * l + 256 * jj;   // own wave's 64-row span
        const float4 hv4 = *(const float4*)(sH + f);
        const float4 cv4 = *(const float4*)(sC + f);
        *(float4*)(hout  + bb + f) = hv4;
        *(float4*)(cout_ + bb + f) = cv4;
    }
}

// =====================  exact fixup (verbatim R9)  =====================
__global__ __launch_bounds__(256) void lstm_fixup(
    const float* __restrict__ x, const float* __restrict__ hx,
    const float* __restrict__ cx, const float* __restrict__ u,
    const float* __restrict__ W_ih, const float* __restrict__ W_hh,
    const float* __restrict__ b_ih, const float* __restrict__ b_hh,
    const float* __restrict__ W_dec, const float* __restrict__ b_dec,
    const unsigned* __restrict__ cnt, const unsigned* __restrict__ list,
    float* __restrict__ out)
{
    const unsigned n = min(*cnt, CAP);
    const unsigned i = blockIdx.x * 256 + threadIdx.x;
    if (i >= n) return;
    const int b = (int)list[i];
    const float x0 = x[2 * (size_t)b], x1 = x[2 * (size_t)b + 1];
    const float uv = u[b];
    float hv[H], cvv[H];
#pragma unroll
    for (int k = 0; k < H; ++k) {
        hv[k]  = hx[(size_t)b * H + k];
        cvv[k] = cx[(size_t)b * H + k];
    }
    float l0 = b_dec[0], l1 = b_dec[1], l2 = b_dec[2];
#pragma unroll 1
    for (int q = 0; q < H; ++q) {
        float gi = (b_ih[q]      + b_hh[q])      + x0 * W_ih[2 * q]          + x1 * W_ih[2 * q + 1];
        float gf = (b_ih[20 + q] + b_hh[20 + q]) + x0 * W_ih[2 * (20 + q)]   + x1 * W_ih[2 * (20 + q) + 1];
        float gg = (b_ih[40 + q] + b_hh[40 + q]) + x0 * W_ih[2 * (40 + q)]   + x1 * W_ih[2 * (40 + q) + 1];
        float go = (b_ih[60 + q] + b_hh[60 + q]) + x0 * W_ih[2 * (60 + q)]   + x1 * W_ih[2 * (60 + q) + 1];
#pragma unroll
        for (int k = 0; k < H; ++k) {
            const float hk = hv[k];
            gi += hk * W_hh[(q)      * H + k];
            gf += hk * W_hh[(20 + q) * H + k];
            gg += hk * W_hh[(40 + q) * H + k];
            go += hk * W_hh[(60 + q) * H + k];
        }
        gi = sigmoidf_stable(gi);
        gf = sigmoidf_stable(gf);
        gg = tanhf(gg);
        go = sigmoidf_stable(go);
        const float cq = gf * cvv[q] + gi * gg;
        const float hq = go * tanhf(cq);
        l0 += hq * W_dec[q];
        l1 += hq * W_dec[20 + q];
        l2 += hq * W_dec[40 + q];
    }
    const float m = fmaxf(fmaxf(l0, l1), l2);
    const float s = expf(l0 - m) + expf(l1 - m) + expf(l2 - m);
    const float lse = m + logf(s);
    const float lp0 = l0 - lse, lp1 = l1 - lse, lp2 = l2 - lse;
    const float p0 = expf(lp0), p1 = expf(lp1), p2 = expf(lp2);
    const float c0 = p0, c1 = c0 + p1, c2 = c1 + p2;
    int ae = (int)(c0 < uv) + (int)(c1 < uv) + (int)(c2 < uv);
    ae = ae > 2 ? 2 : ae;
    out[b] = (float)ae;
    out[(size_t)BATCH + b] = (ae == 0) ? lp0 : ((ae == 1) ? lp1 : lp2);
}

extern "C" void kernel_launch(void* const* d_in, const int* in_sizes, int n_in,
                              void* d_out, int out_size, void* d_ws, size_t ws_size,
                              hipStream_t stream) {
    const float* x     = (const float*)d_in[0];
    const float* hx    = (const float*)d_in[1];
    const float* cx    = (const float*)d_in[2];
    const float* u     = (const float*)d_in[3];
    const float* W_ih  = (const float*)d_in[4];
    const float* W_hh  = (const float*)d_in[5];
    const float* b_ih  = (const float*)d_in[6];
    const float* b_hh  = (const float*)d_in[7];
    const float* W_dec = (const float*)d_in[8];
    const float* b_dec = (const float*)d_in[9];
    float* out = (float*)d_out;
    char* ws = (char*)d_ws;
    unsigned* cnt  = (unsigned*)(ws + CNT_OFF);
    unsigned* list = (unsigned*)(ws + LIST_OFF);

    pack_weights<<<16, 256, 0, stream>>>(W_ih, W_hh, b_ih, b_hh, W_dec, ws);
    lstm_mfma<<<BATCH / 256, 256, 0, stream>>>(x, hx, cx, u, ws, b_dec, out, cnt, list);
    lstm_fixup<<<CAP / 256, 256, 0, stream>>>(x, hx, cx, u, W_ih, W_hh, b_ih, b_hh,
                                              W_dec, b_dec, cnt, list, out);
}

// Round 13
// 121.177 us; speedup vs baseline: 1.6471x; 1.1219x over previous
//
#include <hip/hip_runtime.h>

constexpr int BATCH = 1048576;
constexpr int H = 20;       // hidden
constexpr int BLK = 256;    // threads per block = batch rows per block
constexpr int RS = 21;      // padded LDS row stride (gcd(21,32)=1 -> conflict-free)
constexpr int TILE = BLK * H;   // 5120 floats per tile
constexpr unsigned CAP = 32768;
constexpr float EPS_GUARD = 1e-4f;   // validated R6-R10 for this fast path

// ---- d_ws layout (bytes) ----
constexpr size_t CNT_B  = 0;        // u32 counter
constexpr size_t WPK_B  = 4096;     // packed weights, 1920 floats
constexpr size_t LIST_B = 16384;    // u32[CAP]
// packed float offsets (relative to WPK_B); WHH/WIH/B identical to validated R5-R10:
constexpr int WHH_OFF = 0;      // (q*20+k)*4 + gate {i,f,g,o}
constexpr int WIH_OFF = 1600;   // q*8 + {gate, 4+gate} for x0,x1
constexpr int B_OFF   = 1760;   // q*4 + gate (b_ih+b_hh pre-summed)
constexpr int WD4_OFF = 1840;   // q*4 + a   (W_dec[a][q], a<3; w=0)

typedef float v2f __attribute__((ext_vector_type(2)));
__device__ __forceinline__ v2f splat2(float s) { v2f r; r.x = s; r.y = s; return r; }

// ---- exact path (bit-identical to validated R3/R5-R10) ----
__device__ __forceinline__ float sigmoidf_stable(float z) {
    const float e = expf(-fabsf(z));
    const float n = (z >= 0.0f) ? 1.0f : e;
    return n / (1.0f + e);
}
// ---- fast path (validated R6-R10) ----
__device__ __forceinline__ float fsigmoid(float z) {
    const float e = __expf(-z);
    return __builtin_amdgcn_rcpf(1.0f + e);
}
__device__ __forceinline__ float ftanh(float z) {
    const float e = __expf(2.0f * z);
    return 1.0f - 2.0f * __builtin_amdgcn_rcpf(e + 1.0f);
}

__global__ __launch_bounds__(256) void pack_weights(
    const float* __restrict__ W_ih, const float* __restrict__ W_hh,
    const float* __restrict__ b_ih, const float* __restrict__ b_hh,
    const float* __restrict__ W_dec, char* __restrict__ wsb)
{
    float* ws = (float*)(wsb + WPK_B);
    const int i = blockIdx.x * 256 + threadIdx.x;
    if (i == 0) *(unsigned*)(wsb + CNT_B) = 0u;
    if (i < 400) {
        const int q = i / 20, k = i % 20;
#pragma unroll
        for (int g = 0; g < 4; ++g)
            ws[WHH_OFF + i * 4 + g] = W_hh[(g * 20 + q) * 20 + k];
    }
    if (i < 20) {
#pragma unroll
        for (int g = 0; g < 4; ++g) {
            ws[WIH_OFF + i * 8 + g]     = W_ih[(g * 20 + i) * 2 + 0];
            ws[WIH_OFF + i * 8 + 4 + g] = W_ih[(g * 20 + i) * 2 + 1];
            ws[B_OFF   + i * 4 + g]     = b_ih[g * 20 + i] + b_hh[g * 20 + i];
        }
    }
    if (i < 80) {
        const int q = i >> 2, a = i & 3;
        ws[WD4_OFF + i] = (a < 3) ? W_dec[a * 20 + q] : 0.0f;
    }
}

__global__ __launch_bounds__(BLK) void lstm_coord_kernel(
    const float* __restrict__ x,
    const float* __restrict__ hx,
    const float* __restrict__ cx,
    const float* __restrict__ u,
    const char* __restrict__ wsb,
    const float* __restrict__ b_dec,
    float* __restrict__ out,
    unsigned* __restrict__ cnt,
    unsigned* __restrict__ list)
{
    // LDS used ONLY to coalesce the h/c output stores (R8/R10-validated).
    __shared__ float sH[BLK * RS];
    __shared__ float sC[BLK * RS];

    const float* wpk = (const float*)(wsb + WPK_B);
    const int t = threadIdx.x;
    const size_t base = (size_t)blockIdx.x * TILE;
    const int b = blockIdx.x * BLK + t;
    const int row = t * RS;

    // ---- direct per-row register loads (verbatim R10) ----
    const size_t rowbase = (size_t)b * H;
    v2f hv2[H];
    float cxv[H];
#pragma unroll
    for (int j = 0; j < 5; ++j) {
        const float4 hh = *reinterpret_cast<const float4*>(hx + rowbase + 4 * j);
        hv2[4 * j + 0] = splat2(hh.x); hv2[4 * j + 1] = splat2(hh.y);
        hv2[4 * j + 2] = splat2(hh.z); hv2[4 * j + 3] = splat2(hh.w);
        const float4 cc = *reinterpret_cast<const float4*>(cx + rowbase + 4 * j);
        cxv[4 * j + 0] = cc.x; cxv[4 * j + 1] = cc.y;
        cxv[4 * j + 2] = cc.z; cxv[4 * j + 3] = cc.w;
    }
    const float2 xv = *reinterpret_cast<const float2*>(x + 2 * (size_t)b);
    const v2f x0v = splat2(xv.x);
    const v2f x1v = splat2(xv.y);
    const float uv = u[b];

    // ---- FAST path: per-q ops identical to validated R10; unroll 2 so the
    //      scheduler overlaps iteration q+1's s_load stream with q's compute ----
    float l0 = b_dec[0], l1 = b_dec[1], l2 = b_dec[2];
#pragma unroll 2
    for (int q = 0; q < H; ++q) {
        v2f g01 = *reinterpret_cast<const v2f*>(wpk + B_OFF + 4 * q);
        v2f g23 = *reinterpret_cast<const v2f*>(wpk + B_OFF + 4 * q + 2);
        g01 = g01 + x0v * *reinterpret_cast<const v2f*>(wpk + WIH_OFF + 8 * q);
        g23 = g23 + x0v * *reinterpret_cast<const v2f*>(wpk + WIH_OFF + 8 * q + 2);
        g01 = g01 + x1v * *reinterpret_cast<const v2f*>(wpk + WIH_OFF + 8 * q + 4);
        g23 = g23 + x1v * *reinterpret_cast<const v2f*>(wpk + WIH_OFF + 8 * q + 6);
#pragma unroll
        for (int k = 0; k < H; ++k) {
            const v2f wp01 = *reinterpret_cast<const v2f*>(wpk + WHH_OFF + (q * 20 + k) * 4);
            const v2f wp23 = *reinterpret_cast<const v2f*>(wpk + WHH_OFF + (q * 20 + k) * 4 + 2);
            g01 = g01 + hv2[k] * wp01;
            g23 = g23 + hv2[k] * wp23;
        }
        const float gi = fsigmoid(g01.x);
        const float gf = fsigmoid(g01.y);
        const float gg = ftanh(g23.x);
        const float go = fsigmoid(g23.y);
        const float cq = gf * cxv[q] + gi * gg;
        const float hq = go * ftanh(cq);
        sC[row + q] = cq;       // own row only
        sH[row + q] = hq;       // own row only
        const float4 wd = *reinterpret_cast<const float4*>(wpk + WD4_OFF + 4 * q);
        l0 += hq * wd.x;
        l1 += hq * wd.y;
        l2 += hq * wd.z;
    }

    // ---- fast softmax + inverse-CDF sample (verbatim R10) ----
    const float m = fmaxf(fmaxf(l0, l1), l2);
    const float s = __expf(l0 - m) + __expf(l1 - m) + __expf(l2 - m);
    const float lse = m + __logf(s);
    const float lp0 = l0 - lse, lp1 = l1 - lse, lp2 = l2 - lse;
    const float p0 = __expf(lp0), p1 = __expf(lp1), p2 = __expf(lp2);
    const float c0 = p0;
    const float c1 = c0 + p1;
    const float c2 = c1 + p2;
    int acti = (int)(c0 < uv) + (int)(c1 < uv) + (int)(c2 < uv);
    acti = acti > 2 ? 2 : acti;
    out[b] = (float)acti;
    out[(size_t)BATCH + b] = (acti == 0) ? lp0 : ((acti == 1) ? lp1 : lp2);

    // ---- guard -> sparse fixup list (exact path lives in lstm_fixup) ----
    const float d0 = fabsf(c0 - uv), d1 = fabsf(c1 - uv), d2 = fabsf(c2 - uv);
    if (fminf(fminf(d0, d1), d2) < EPS_GUARD) {
        const unsigned i = atomicAdd(cnt, 1u);
        if (i < CAP) list[i] = (unsigned)b;
    }

    __syncthreads();   // all rows of sH/sC finalized

    // ---- coalesced LDS->global stores of h/c tiles (verbatim R8/R10) ----
    float* hout  = out + 2 * (size_t)BATCH;
    float* cout_ = hout + (size_t)H * BATCH;
#pragma unroll
    for (int j = 0; j < 5; ++j) {
        const int g = 4 * (t + BLK * j);
        float4 v, w;
#pragma unroll
        for (int e = 0; e < 4; ++e) {
            const int gg = g + e;
            (&v.x)[e] = sH[gg + gg / H];
            (&w.x)[e] = sC[gg + gg / H];
        }
        *reinterpret_cast<float4*>(hout  + base + g) = v;
        *reinterpret_cast<float4*>(cout_ + base + g) = w;
    }
}

// ---- exact fixup on the sparse risky list (verbatim R9/R12-validated) ----
__global__ __launch_bounds__(256) void lstm_fixup(
    const float* __restrict__ x, const float* __restrict__ hx,
    const float* __restrict__ cx, const float* __restrict__ u,
    const float* __restrict__ W_ih, const float* __restrict__ W_hh,
    const float* __restrict__ b_ih, const float* __restrict__ b_hh,
    const float* __restrict__ W_dec, const float* __restrict__ b_dec,
    const unsigned* __restrict__ cnt, const unsigned* __restrict__ list,
    float* __restrict__ out)
{
    const unsigned n = min(*cnt, CAP);
    const unsigned i = blockIdx.x * 256 + threadIdx.x;
    if (i >= n) return;
    const int b = (int)list[i];
    const float x0 = x[2 * (size_t)b], x1 = x[2 * (size_t)b + 1];
    const float uv = u[b];
    float hv[H], cvv[H];
#pragma unroll
    for (int k = 0; k < H; ++k) {
        hv[k]  = hx[(size_t)b * H + k];
        cvv[k] = cx[(size_t)b * H + k];
    }
    float l0 = b_dec[0], l1 = b_dec[1], l2 = b_dec[2];
#pragma unroll 1
    for (int q = 0; q < H; ++q) {
        float gi = (b_ih[q]      + b_hh[q])      + x0 * W_ih[2 * q]          + x1 * W_ih[2 * q + 1];
        float gf = (b_ih[20 + q] + b_hh[20 + q]) + x0 * W_ih[2 * (20 + q)]   + x1 * W_ih[2 * (20 + q) + 1];
        float gg = (b_ih[40 + q] + b_hh[40 + q]) + x0 * W_ih[2 * (40 + q)]   + x1 * W_ih[2 * (40 + q) + 1];
        float go = (b_ih[60 + q] + b_hh[60 + q]) + x0 * W_ih[2 * (60 + q)]   + x1 * W_ih[2 * (60 + q) + 1];
#pragma unroll
        for (int k = 0; k < H; ++k) {
            const float hk = hv[k];
            gi += hk * W_hh[(q)      * H + k];
            gf += hk * W_hh[(20 + q) * H + k];
            gg += hk * W_hh[(40 + q) * H + k];
            go += hk * W_hh[(60 + q) * H + k];
        }
        gi = sigmoidf_stable(gi);
        gf = sigmoidf_stable(gf);
        gg = tanhf(gg);
        go = sigmoidf_stable(go);
        const float cq = gf * cvv[q] + gi * gg;
        const float hq = go * tanhf(cq);
        l0 += hq * W_dec[q];
        l1 += hq * W_dec[20 + q];
        l2 += hq * W_dec[40 + q];
    }
    const float m = fmaxf(fmaxf(l0, l1), l2);
    const float s = expf(l0 - m) + expf(l1 - m) + expf(l2 - m);
    const float lse = m + logf(s);
    const float lp0 = l0 - lse, lp1 = l1 - lse, lp2 = l2 - lse;
    const float p0 = expf(lp0), p1 = expf(lp1), p2 = expf(lp2);
    const float c0 = p0, c1 = c0 + p1, c2 = c1 + p2;
    int ae = (int)(c0 < uv) + (int)(c1 < uv) + (int)(c2 < uv);
    ae = ae > 2 ? 2 : ae;
    out[b] = (float)ae;
    out[(size_t)BATCH + b] = (ae == 0) ? lp0 : ((ae == 1) ? lp1 : lp2);
}

extern "C" void kernel_launch(void* const* d_in, const int* in_sizes, int n_in,
                              void* d_out, int out_size, void* d_ws, size_t ws_size,
                              hipStream_t stream) {
    const float* x     = (const float*)d_in[0];
    const float* hx    = (const float*)d_in[1];
    const float* cx    = (const float*)d_in[2];
    const float* u     = (const float*)d_in[3];
    const float* W_ih  = (const float*)d_in[4];
    const float* W_hh  = (const float*)d_in[5];
    const float* b_ih  = (const float*)d_in[6];
    const float* b_hh  = (const float*)d_in[7];
    const float* W_dec = (const float*)d_in[8];
    const float* b_dec = (const float*)d_in[9];
    float* out = (float*)d_out;
    char* wsb = (char*)d_ws;
    unsigned* cnt  = (unsigned*)(wsb + CNT_B);
    unsigned* list = (unsigned*)(wsb + LIST_B);

    pack_weights<<<2, 256, 0, stream>>>(W_ih, W_hh, b_ih, b_hh, W_dec, wsb);
    lstm_coord_kernel<<<BATCH / BLK, BLK, 0, stream>>>(
        x, hx, cx, u, wsb, b_dec, out, cnt, list);
    lstm_fixup<<<CAP / 256, 256, 0, stream>>>(x, hx, cx, u, W_ih, W_hh, b_ih, b_hh,
                                              W_dec, b_dec, cnt, list, out);
}